// Round 1
// baseline (456.416 us; speedup 1.0000x reference)
//
#include <hip/hip_runtime.h>
#include <math.h>

// GNN message-passing layer — linearity restructure + bf16 MFMA + wide gather.
//   agg[r] = (sum x_snd) @ Wm_x^T + (sum e_attr) @ Wm_e^T   (message fn is linear)
// Pipeline:
//   memset counts
//   prep:  Wcat=[W1a | W1b@Wm]->bf16, W2/Wn->bf16, nodes->bf16, hist(receivers)
//   scan1/2/3: parallel exclusive scan -> row_ptr, cursor
//   build: CSR perm/snds
//   aggsum: S[r] = [sum nodes_bf[snd] | sum eattr] -> bf16
//           (wave/receiver; dwordx4 gathers: 16 lanes/row -> 4 node rows per load,
//            8 eattr rows per load; 16-edge step + tier-masked tail -> one
//            CSR round + one gather round for deg<=15; shfl_xor group reduce)
//   node0:  h(bf16) = LN(relu([nodes_bf|S] @ Wcat^T + b1))     K=288
//   node12: out     = LN(nodes_bf @ Wn^T + LN(relu(h @ W2^T + b2)))   (fused)
// GEMMs: bf16 LDS tiles (16B copy staging) -> v_mfma_f32_16x16x32_bf16.
// Block tile M=64 x N=128, BK=32, 4 waves 2x2, each wave 32x64 (2x4 16x16 tiles).

#define THREADS 256
#define BM 64
#define BK 32
#define APB 40   // LDS row pitch in bf16 (80B rows -> <=2-way bank alias, free)
#define BP 132   // Cs row pitch (floats)

typedef __attribute__((ext_vector_type(8))) short bf16x8;
typedef __attribute__((ext_vector_type(4))) float f32x4;

struct GemmSmem {
  unsigned short As[BM][APB];
  unsigned short Bs[128][APB];
};
struct EpiSmem {
  float Cs[BM][BP];
  float psum[BM][4];
  float psq[BM][4];
  float mu[BM];
  float rs[BM];
};
union NodeSmem { GemmSmem g; EpiSmem e; };

union BF8 { bf16x8 v; ushort4 q[2]; };

__device__ __forceinline__ unsigned short f2bf(float x) {
  union { float f; unsigned u; } c; c.f = x;
  unsigned u = c.u;
  u += 0x7fffu + ((u >> 16) & 1u);   // RNE
  return (unsigned short)(u >> 16);
}
__device__ __forceinline__ float bf2f(unsigned h) {
  union { unsigned u; float f; } c; c.u = h << 16; return c.f;
}
__device__ __forceinline__ ushort4 cvt4(float4 v) {
  ushort4 p; p.x = f2bf(v.x); p.y = f2bf(v.y); p.z = f2bf(v.z); p.w = f2bf(v.w);
  return p;
}

// ---------------- prep: weight fold/convert + nodes->bf16 + receiver histogram ----
__global__ __launch_bounds__(256) void prep_kernel(
    const float* __restrict__ W1, const float* __restrict__ Wm,
    const float* __restrict__ W2, const float* __restrict__ Wn,
    const float* __restrict__ nodes, const int* __restrict__ eidx,
    unsigned short* __restrict__ Wcat, unsigned short* __restrict__ W2b,
    unsigned short* __restrict__ Wnb, unsigned short* __restrict__ nodes_bf,
    int* __restrict__ counts, int Nn, int E, int nconv) {
  const int b = blockIdx.x, tid = threadIdx.x;
  if (b < 128) {
    for (int t = tid; t < 288; t += 256) {
      float v;
      if (t < 128) {
        v = W1[(size_t)b * 256 + t];
      } else {
        int u = t - 128;
        float s = 0.f;
#pragma unroll 8
        for (int k = 0; k < 128; ++k)
          s += W1[(size_t)b * 256 + 128 + k] * Wm[(size_t)k * 160 + u];
        v = s;
      }
      Wcat[(size_t)b * 288 + t] = f2bf(v);
    }
  } else if (b < 144) {
    int idx = (b - 128) * 1024 + tid * 4;
    *(ushort4*)&W2b[idx] = cvt4(*(const float4*)&W2[idx]);
  } else if (b < 160) {
    int idx = (b - 144) * 1024 + tid * 4;
    *(ushort4*)&Wnb[idx] = cvt4(*(const float4*)&Wn[idx]);
  } else if (b < 160 + nconv) {
    int idx = ((b - 160) * 256 + tid) * 4;
    if (idx < Nn * 128)
      *(ushort4*)&nodes_bf[idx] = cvt4(*(const float4*)&nodes[idx]);
  } else {
    int i = (b - 160 - nconv) * 256 + tid;
    if (i < E) atomicAdd(&counts[eidx[E + i]], 1);
  }
}

// ---------------- parallel exclusive scan over counts ----------------
__global__ __launch_bounds__(256) void scan1_kernel(const int* __restrict__ counts,
                                                    int* __restrict__ bsum, int Nn) {
  __shared__ int red[256];
  const int tid = threadIdx.x;
  int base = blockIdx.x * 2048 + tid * 8;
  int s = 0;
#pragma unroll
  for (int i = 0; i < 8; ++i) {
    int idx = base + i;
    if (idx < Nn) s += counts[idx];
  }
  red[tid] = s;
  __syncthreads();
#pragma unroll
  for (int off = 128; off; off >>= 1) {
    if (tid < off) red[tid] += red[tid + off];
    __syncthreads();
  }
  if (tid == 0) bsum[blockIdx.x] = red[0];
}

__global__ __launch_bounds__(256) void scan2_kernel(const int* __restrict__ bsum,
                                                    int* __restrict__ boff, int NB) {
  __shared__ int arr[256];
  const int tid = threadIdx.x;
  int v = (tid < NB) ? bsum[tid] : 0;
  arr[tid] = v;
  __syncthreads();
  for (int off = 1; off < 256; off <<= 1) {
    int t2 = (tid >= off) ? arr[tid - off] : 0;
    __syncthreads();
    arr[tid] += t2;
    __syncthreads();
  }
  if (tid < NB) boff[tid] = arr[tid] - v;   // exclusive
}

__global__ __launch_bounds__(256) void scan3_kernel(const int* __restrict__ counts,
                                                    const int* __restrict__ boff,
                                                    int* __restrict__ row_ptr,
                                                    int* __restrict__ cursor, int Nn) {
  __shared__ int arr[256];
  const int tid = threadIdx.x;
  int base = blockIdx.x * 2048 + tid * 8;
  int c[8];
  int s = 0;
#pragma unroll
  for (int i = 0; i < 8; ++i) {
    int idx = base + i;
    c[i] = (idx < Nn) ? counts[idx] : 0;
    s += c[i];
  }
  arr[tid] = s;
  __syncthreads();
  for (int off = 1; off < 256; off <<= 1) {
    int t2 = (tid >= off) ? arr[tid - off] : 0;
    __syncthreads();
    arr[tid] += t2;
    __syncthreads();
  }
  int run = arr[tid] - s + boff[blockIdx.x];
#pragma unroll
  for (int i = 0; i < 8; ++i) {
    int idx = base + i;
    if (idx < Nn) {
      row_ptr[idx] = run;
      cursor[idx] = run;
    }
    run += c[i];
  }
}

__global__ __launch_bounds__(256) void build_kernel(const int* __restrict__ eidx,
                                                    int* __restrict__ cursor,
                                                    int* __restrict__ perm,
                                                    int* __restrict__ snds, int E) {
  int i = blockIdx.x * 256 + threadIdx.x;
  if (i < E) {
    int r = eidx[E + i];
    int pos = atomicAdd(&cursor[r], 1);
    perm[pos] = i;
    snds[pos] = eidx[i];
  }
}

// ------- per-receiver input sums: dwordx4 gathers (4 rows/load), group reduce ----
__device__ __forceinline__ void acc8(float s[8], uint4 v) {
  s[0] += bf2f(v.x & 0xffffu); s[1] += bf2f(v.x >> 16);
  s[2] += bf2f(v.y & 0xffffu); s[3] += bf2f(v.y >> 16);
  s[4] += bf2f(v.z & 0xffffu); s[5] += bf2f(v.z >> 16);
  s[6] += bf2f(v.w & 0xffffu); s[7] += bf2f(v.w >> 16);
}

__global__ __launch_bounds__(256) void aggsum_kernel(
    const unsigned short* __restrict__ nodes_bf, const float* __restrict__ eattr,
    const int* __restrict__ row_ptr, const int* __restrict__ rend,
    const int* __restrict__ perm, const int* __restrict__ snds,
    unsigned short* __restrict__ S, int Nn) {
  const int wid = blockIdx.x * 4 + (threadIdx.x >> 6);
  if (wid >= Nn) return;
  const int lane = threadIdx.x & 63;
  const int start = row_ptr[wid];
  const int end = rend[wid];

  const uint4* nodes16 = (const uint4*)nodes_bf;   // node row = 16 uint4 (256 B)
  const float4* eattr4 = (const float4*)eattr;     // eattr row = 8 float4 (128 B)

  const int g4 = lane >> 4, l16 = lane & 15;   // 4 groups x 16 lanes: node rows
  const int g8 = lane >> 3, l8 = lane & 7;     // 8 groups x 8 lanes:  eattr rows

  float sn[8] = {0.f, 0.f, 0.f, 0.f, 0.f, 0.f, 0.f, 0.f};  // cols 8*l16 .. +7
  float se[4] = {0.f, 0.f, 0.f, 0.f};                      // cols 4*l8 .. +3

  for (int base = start; base < end; base += 64) {
    const int cnt = min(64, end - base);
    int sv = 0, pv = 0;
    if (lane < cnt) { sv = snds[base + lane]; pv = perm[base + lane]; }

    int t = 0;
    // full 16-edge steps: 4 node loads + 2 eattr loads in flight, no masks
    for (; t + 16 <= cnt; t += 16) {
      int i0 = __shfl(sv, t + g4);
      int i1 = __shfl(sv, t + 4 + g4);
      int i2 = __shfl(sv, t + 8 + g4);
      int i3 = __shfl(sv, t + 12 + g4);
      int p0 = __shfl(pv, t + g8);
      int p1 = __shfl(pv, t + 8 + g8);
      uint4 v0 = nodes16[(size_t)i0 * 16 + l16];
      uint4 v1 = nodes16[(size_t)i1 * 16 + l16];
      uint4 v2 = nodes16[(size_t)i2 * 16 + l16];
      uint4 v3 = nodes16[(size_t)i3 * 16 + l16];
      float4 e0 = eattr4[(size_t)p0 * 8 + l8];
      float4 e1 = eattr4[(size_t)p1 * 8 + l8];
      acc8(sn, v0); acc8(sn, v1); acc8(sn, v2); acc8(sn, v3);
      se[0] += e0.x + e1.x; se[1] += e0.y + e1.y;
      se[2] += e0.z + e1.z; se[3] += e0.w + e1.w;
    }
    // masked remainder (up to 15 edges) — tier conditions are wave-uniform,
    // so unneeded wide loads are skipped entirely; per-lane masks on the adds.
    if (t < cnt) {
      int i0 = __shfl(sv, t + g4);           // shfl index <= 63 always (t <= 56)
      int p0 = __shfl(pv, t + g8);
      uint4 v0 = nodes16[(size_t)i0 * 16 + l16];
      float4 e0 = eattr4[(size_t)p0 * 8 + l8];
      if (t + 4 < cnt) {
        int i1 = __shfl(sv, t + 4 + g4);
        uint4 v1 = nodes16[(size_t)i1 * 16 + l16];
        if (t + 4 + g4 < cnt) acc8(sn, v1);
      }
      if (t + 8 < cnt) {
        int i2 = __shfl(sv, t + 8 + g4);
        int p1 = __shfl(pv, t + 8 + g8);
        uint4 v2 = nodes16[(size_t)i2 * 16 + l16];
        float4 e1 = eattr4[(size_t)p1 * 8 + l8];
        if (t + 8 + g4 < cnt) acc8(sn, v2);
        if (t + 8 + g8 < cnt) {
          se[0] += e1.x; se[1] += e1.y; se[2] += e1.z; se[3] += e1.w;
        }
      }
      if (t + 12 < cnt) {
        int i3 = __shfl(sv, t + 12 + g4);
        uint4 v3 = nodes16[(size_t)i3 * 16 + l16];
        if (t + 12 + g4 < cnt) acc8(sn, v3);
      }
      if (t + g4 < cnt) acc8(sn, v0);
      if (t + g8 < cnt) {
        se[0] += e0.x; se[1] += e0.y; se[2] += e0.z; se[3] += e0.w;
      }
    }
  }

  // cross-group reduction: node sums over 4 groups, eattr sums over 8 groups
#pragma unroll
  for (int j = 0; j < 8; ++j) {
    sn[j] += __shfl_xor(sn[j], 16);
    sn[j] += __shfl_xor(sn[j], 32);
  }
#pragma unroll
  for (int j = 0; j < 4; ++j) {
    se[j] += __shfl_xor(se[j], 8);
    se[j] += __shfl_xor(se[j], 16);
    se[j] += __shfl_xor(se[j], 32);
  }

  // S row = 160 bf16 = 20 uint4: [128 node-sum | 32 eattr-sum]
  if (lane < 16) {
    uint4 o;
    o.x = (unsigned)f2bf(sn[0]) | ((unsigned)f2bf(sn[1]) << 16);
    o.y = (unsigned)f2bf(sn[2]) | ((unsigned)f2bf(sn[3]) << 16);
    o.z = (unsigned)f2bf(sn[4]) | ((unsigned)f2bf(sn[5]) << 16);
    o.w = (unsigned)f2bf(sn[6]) | ((unsigned)f2bf(sn[7]) << 16);
    ((uint4*)S)[(size_t)wid * 20 + l16] = o;
  }
  if (lane < 8) {
    uint2 o;
    o.x = (unsigned)f2bf(se[0]) | ((unsigned)f2bf(se[1]) << 16);
    o.y = (unsigned)f2bf(se[2]) | ((unsigned)f2bf(se[3]) << 16);
    ((uint2*)S)[(size_t)wid * 40 + 32 + l8] = o;
  }
}

// ---------------- shared GEMM pieces ----------------
__device__ __forceinline__ void gemm_chunk(const GemmSmem& sm, int tid,
                                           f32x4 acc[2][4]) {
  const int lane = tid & 63;
  const int quad = lane >> 4;
  const int lm = lane & 15;
  const int wid = tid >> 6;
  const int wy = wid >> 1, wx = wid & 1;

  bf16x8 af[2], bf[4];
#pragma unroll
  for (int mt = 0; mt < 2; ++mt)
    af[mt] = *(const bf16x8*)&sm.As[32 * wy + 16 * mt + lm][quad * 8];
#pragma unroll
  for (int nt = 0; nt < 4; ++nt)
    bf[nt] = *(const bf16x8*)&sm.Bs[64 * wx + 16 * nt + lm][quad * 8];
#pragma unroll
  for (int mt = 0; mt < 2; ++mt)
#pragma unroll
    for (int nt = 0; nt < 4; ++nt)
      acc[mt][nt] = __builtin_amdgcn_mfma_f32_16x16x32_bf16(
          af[mt], bf[nt], acc[mt][nt], 0, 0, 0);
}

__device__ __forceinline__ void gemm_k128(const unsigned short* __restrict__ A,
                                          const unsigned short* __restrict__ W,
                                          int row0, int Nn, GemmSmem& g, int tid,
                                          f32x4 acc[2][4]) {
  for (int kc = 0; kc < 128; kc += BK) {
    {
      int r = tid >> 2, u = tid & 3;
      int row = row0 + r;
      if (row >= Nn) row = Nn - 1;
      BF8 t;
      t.v = *(const bf16x8*)&A[(size_t)row * 128 + kc + 8 * u];
      *(ushort4*)&g.As[r][8 * u] = t.q[0];
      *(ushort4*)&g.As[r][8 * u + 4] = t.q[1];
    }
#pragma unroll
    for (int c = 0; c < 2; ++c) {
      int f = tid + 256 * c;
      int n = f >> 2, u = f & 3;
      BF8 t;
      t.v = *(const bf16x8*)&W[(size_t)n * 128 + kc + 8 * u];
      *(ushort4*)&g.Bs[n][8 * u] = t.q[0];
      *(ushort4*)&g.Bs[n][8 * u + 4] = t.q[1];
    }
    __syncthreads();
    gemm_chunk(g, tid, acc);
    __syncthreads();
  }
}

__device__ __forceinline__ void ln_stats(EpiSmem& e, int tid) {
  {
    int q = tid & 3, r = tid >> 2;
    float s = 0.f, s2 = 0.f;
#pragma unroll 8
    for (int j = q * 32; j < q * 32 + 32; ++j) {
      float x = e.Cs[r][j];
      s += x;
      s2 += x * x;
    }
    e.psum[r][q] = s;
    e.psq[r][q] = s2;
  }
  __syncthreads();
  if (tid < BM) {
    float S_ = 0.f, S2 = 0.f;
#pragma unroll
    for (int q = 0; q < 4; ++q) {
      S_ += e.psum[tid][q];
      S2 += e.psq[tid][q];
    }
    float m = S_ * (1.f / 128.f);
    float var = S2 * (1.f / 128.f) - m * m;
    e.mu[tid] = m;
    e.rs[tid] = rsqrtf(var + 1e-5f);
  }
  __syncthreads();
}

// ---------------- node0: h = LN(relu([nodes_bf|S] @ Wcat^T + b1)), K=288 --------
__global__ __launch_bounds__(THREADS, 4) void node0_kernel(
    const unsigned short* __restrict__ A0, const unsigned short* __restrict__ A1,
    const unsigned short* __restrict__ Wb, const float* __restrict__ bias,
    const float* __restrict__ g, const float* __restrict__ bln,
    unsigned short* __restrict__ outb, int Nn) {
  __shared__ NodeSmem sm;
  const int tid = threadIdx.x;
  const int row0 = blockIdx.x * BM;

  f32x4 acc[2][4];
#pragma unroll
  for (int mt = 0; mt < 2; ++mt)
#pragma unroll
    for (int nt = 0; nt < 4; ++nt) acc[mt][nt] = (f32x4)0.f;

  for (int kc = 0; kc < 288; kc += BK) {
    {
      int r = tid >> 2, u = tid & 3;
      int k = kc + 8 * u;
      int row = row0 + r;
      if (row >= Nn) row = Nn - 1;
      BF8 t;
      if (kc >= 128)
        t.v = *(const bf16x8*)&A1[(size_t)row * 160 + (k - 128)];
      else
        t.v = *(const bf16x8*)&A0[(size_t)row * 128 + k];
      *(ushort4*)&sm.g.As[r][8 * u] = t.q[0];
      *(ushort4*)&sm.g.As[r][8 * u + 4] = t.q[1];
    }
#pragma unroll
    for (int c = 0; c < 2; ++c) {
      int f = tid + 256 * c;
      int n = f >> 2, u = f & 3;
      BF8 t;
      t.v = *(const bf16x8*)&Wb[(size_t)n * 288 + kc + 8 * u];
      *(ushort4*)&sm.g.Bs[n][8 * u] = t.q[0];
      *(ushort4*)&sm.g.Bs[n][8 * u + 4] = t.q[1];
    }
    __syncthreads();
    gemm_chunk(sm.g, tid, acc);
    __syncthreads();
  }

  const int lane = tid & 63;
  const int quad = lane >> 4;
  const int lm = lane & 15;
  const int wid = tid >> 6;
  const int wy = wid >> 1, wx = wid & 1;

  float bval[4];
#pragma unroll
  for (int nt = 0; nt < 4; ++nt) bval[nt] = bias[64 * wx + 16 * nt + lm];
#pragma unroll
  for (int mt = 0; mt < 2; ++mt)
#pragma unroll
    for (int i = 0; i < 4; ++i) {
      int r = 32 * wy + 16 * mt + quad * 4 + i;
#pragma unroll
      for (int nt = 0; nt < 4; ++nt) {
        int col = 64 * wx + 16 * nt + lm;
        sm.e.Cs[r][col] = fmaxf(acc[mt][nt][i] + bval[nt], 0.f);
      }
    }
  __syncthreads();
  ln_stats(sm.e, tid);

#pragma unroll 4
  for (int s = 0; s < 32; ++s) {
    int flat = tid + THREADS * s;
    int r = flat >> 7, j = flat & 127;
    int row = row0 + r;
    if (row < Nn) {
      float x = sm.e.Cs[r][j];
      outb[(size_t)row * 128 + j] =
          f2bf((x - sm.e.mu[r]) * sm.e.rs[r] * g[j] + bln[j]);
    }
  }
}

// ------- node12 (fused): out = LN(nodes@Wn^T + LN(relu(h@W2^T + b2))) ----------
__global__ __launch_bounds__(THREADS, 3) void node12_kernel(
    const unsigned short* __restrict__ h_bf,
    const unsigned short* __restrict__ nodes_bf,
    const unsigned short* __restrict__ W2b, const unsigned short* __restrict__ Wnb,
    const float* __restrict__ b2, const float* __restrict__ g2,
    const float* __restrict__ bl2, const float* __restrict__ gf,
    const float* __restrict__ blf, float* __restrict__ out, int Nn) {
  __shared__ GemmSmem g;
  __shared__ EpiSmem e;
  const int tid = threadIdx.x;
  const int row0 = blockIdx.x * BM;
  const int lane = tid & 63;
  const int quad = lane >> 4;
  const int lm = lane & 15;
  const int wid = tid >> 6;
  const int wy = wid >> 1, wx = wid & 1;

  f32x4 acc[2][4];
#pragma unroll
  for (int mt = 0; mt < 2; ++mt)
#pragma unroll
    for (int nt = 0; nt < 4; ++nt) acc[mt][nt] = (f32x4)0.f;

  // ---- phase A: h @ W2^T, relu+b2, LN2 -> Cs (node_out tile) ----
  gemm_k128(h_bf, W2b, row0, Nn, g, tid, acc);

  float bval[4];
#pragma unroll
  for (int nt = 0; nt < 4; ++nt) bval[nt] = b2[64 * wx + 16 * nt + lm];
#pragma unroll
  for (int mt = 0; mt < 2; ++mt)
#pragma unroll
    for (int i = 0; i < 4; ++i) {
      int r = 32 * wy + 16 * mt + quad * 4 + i;
#pragma unroll
      for (int nt = 0; nt < 4; ++nt) {
        int col = 64 * wx + 16 * nt + lm;
        e.Cs[r][col] = fmaxf(acc[mt][nt][i] + bval[nt], 0.f);
      }
    }
  __syncthreads();
  ln_stats(e, tid);

  // rewrite Cs in normalized form (= node_out)
#pragma unroll 4
  for (int s = 0; s < 32; ++s) {
    int flat = tid + THREADS * s;
    int r = flat >> 7, j = flat & 127;
    float x = e.Cs[r][j];
    e.Cs[r][j] = (x - e.mu[r]) * e.rs[r] * g2[j] + bl2[j];
  }
  __syncthreads();

  // ---- phase B: nodes @ Wn^T + node_out, final LN ----
#pragma unroll
  for (int mt = 0; mt < 2; ++mt)
#pragma unroll
    for (int nt = 0; nt < 4; ++nt) acc[mt][nt] = (f32x4)0.f;

  gemm_k128(nodes_bf, Wnb, row0, Nn, g, tid, acc);

#pragma unroll
  for (int mt = 0; mt < 2; ++mt)
#pragma unroll
    for (int i = 0; i < 4; ++i) {
      int r = 32 * wy + 16 * mt + quad * 4 + i;
#pragma unroll
      for (int nt = 0; nt < 4; ++nt) {
        int col = 64 * wx + 16 * nt + lm;
        e.Cs[r][col] = acc[mt][nt][i] + e.Cs[r][col];
      }
    }
  __syncthreads();
  ln_stats(e, tid);

#pragma unroll 4
  for (int s = 0; s < 32; ++s) {
    int flat = tid + THREADS * s;
    int r = flat >> 7, j = flat & 127;
    int row = row0 + r;
    if (row < Nn) {
      float x = e.Cs[r][j];
      out[(size_t)row * 128 + j] =
          (x - e.mu[r]) * e.rs[r] * gf[j] + blf[j];
    }
  }
}

extern "C" void kernel_launch(void* const* d_in, const int* in_sizes, int n_in,
                              void* d_out, int out_size, void* d_ws, size_t ws_size,
                              hipStream_t stream) {
  const float* nodes = (const float*)d_in[0];
  const int* eidx    = (const int*)d_in[1];
  const float* eattr = (const float*)d_in[2];
  const float* Wm    = (const float*)d_in[3];
  const float* Wn    = (const float*)d_in[4];
  const float* W1    = (const float*)d_in[5];
  const float* b1    = (const float*)d_in[6];
  const float* g1    = (const float*)d_in[7];
  const float* bl1   = (const float*)d_in[8];
  const float* W2    = (const float*)d_in[9];
  const float* b2    = (const float*)d_in[10];
  const float* g2    = (const float*)d_in[11];
  const float* bl2   = (const float*)d_in[12];
  const float* gf    = (const float*)d_in[13];
  const float* blf   = (const float*)d_in[14];
  float* out = (float*)d_out;

  const int Nn = in_sizes[0] / 128;   // 100000
  const int E  = in_sizes[2] / 32;    // 800000

  // workspace layout (all 16B-aligned)
  int* counts  = (int*)d_ws;                       // [Nn]
  int* row_ptr = counts + Nn;                      // [Nn]
  int* cursor  = row_ptr + Nn;                     // [Nn] (segment ends after build)
  int* bsum    = cursor + Nn;                      // [256]
  int* boff    = bsum + 256;                       // [256]
  int* perm    = boff + 256;                       // [E]
  int* snds    = perm + E;                         // [E]
  unsigned short* Wcat     = (unsigned short*)(snds + E);       // [128*288]
  unsigned short* W2b      = Wcat + 128 * 288;                  // [128*128]
  unsigned short* Wnb      = W2b + 128 * 128;                   // [128*128]
  unsigned short* nodes_bf = Wnb + 128 * 128;                   // [Nn*128]
  unsigned short* h_bf     = nodes_bf + (size_t)Nn * 128;       // [Nn*128]
  unsigned short* S_bf     = h_bf + (size_t)Nn * 128;           // [Nn*160]

  hipMemsetAsync(counts, 0, (size_t)Nn * sizeof(int), stream);

  const int nconv = (Nn * 32 + 255) / 256;   // nodes float4 chunks
  const int nhist = (E + 255) / 256;
  const int NB = (Nn + 2047) / 2048;
  const int ngrid = (Nn + BM - 1) / BM;

  prep_kernel<<<160 + nconv + nhist, 256, 0, stream>>>(
      W1, Wm, W2, Wn, nodes, eidx, Wcat, W2b, Wnb, nodes_bf, counts, Nn, E, nconv);
  scan1_kernel<<<NB, 256, 0, stream>>>(counts, bsum, Nn);
  scan2_kernel<<<1, 256, 0, stream>>>(bsum, boff, NB);
  scan3_kernel<<<NB, 256, 0, stream>>>(counts, boff, row_ptr, cursor, Nn);
  build_kernel<<<nhist, 256, 0, stream>>>(eidx, cursor, perm, snds, E);
  aggsum_kernel<<<(Nn + 3) / 4, 256, 0, stream>>>(nodes_bf, eattr, row_ptr, cursor,
                                                  perm, snds, S_bf, Nn);
  node0_kernel<<<ngrid, THREADS, 0, stream>>>(nodes_bf, S_bf, Wcat, b1, g1, bl1,
                                              h_bf, Nn);
  node12_kernel<<<ngrid, THREADS, 0, stream>>>(h_bf, nodes_bf, W2b, Wnb, b2, g2,
                                               bl2, gf, blf, out, Nn);
}

// Round 2
// 425.919 us; speedup vs baseline: 1.0716x; 1.0716x over previous
//
#include <hip/hip_runtime.h>
#include <math.h>

// GNN message-passing layer — linearity restructure + bf16 MFMA + ILP'd gather.
//   agg[r] = (sum x_snd) @ Wm_x^T + (sum e_attr) @ Wm_e^T   (message fn is linear)
// Pipeline:
//   memset counts
//   prep:  Wcat=[W1a | W1b@Wm]->bf16, W2/Wn->bf16, nodes->bf16, hist(receivers)
//   scan1/2/3: parallel exclusive scan -> row_ptr, cursor
//   build: CSR perm/snds
//   aggsum: S[r] = [sum nodes_bf[snd] | sum eattr] -> bf16
//           (wave/receiver, 64-index shfl-prefetch, 4-edge unroll -> 6 loads in flight)
//   node_fused: h = LN(relu([nodes_bf|S] @ Wcat^T + b1))         (h stays in LDS)
//               out = LN(nodes_bf @ Wn^T + LN(relu(h @ W2^T + b2)))
//     (node0+node12 fused per 64-row tile: kills the 51 MB h_bf HBM round-trip;
//      phase-B A-fragments staged from Cs in LDS with the same RNE f32->bf16
//      convert node0 used for h_bf, so results are bit-identical.)
// GEMMs: bf16 LDS tiles (16B copy staging) -> v_mfma_f32_16x16x32_bf16.
// Block tile M=64 x N=128, BK=32, 4 waves 2x2, each wave 32x64 (2x4 16x16 tiles).

#define THREADS 256
#define BM 64
#define BK 32
#define APB 40   // LDS row pitch in bf16 (80B rows -> <=2-way bank alias, free)
#define BP 132   // Cs row pitch (floats)

typedef __attribute__((ext_vector_type(8))) short bf16x8;
typedef __attribute__((ext_vector_type(4))) float f32x4;

struct GemmSmem {
  unsigned short As[BM][APB];
  unsigned short Bs[128][APB];
};
struct EpiSmem {
  float Cs[BM][BP];
  float psum[BM][4];
  float psq[BM][4];
  float mu[BM];
  float rs[BM];
};

union BF8 { bf16x8 v; ushort4 q[2]; };

__device__ __forceinline__ unsigned short f2bf(float x) {
  union { float f; unsigned u; } c; c.f = x;
  unsigned u = c.u;
  u += 0x7fffu + ((u >> 16) & 1u);   // RNE
  return (unsigned short)(u >> 16);
}
__device__ __forceinline__ float bf2f(unsigned h) {
  union { unsigned u; float f; } c; c.u = h << 16; return c.f;
}
__device__ __forceinline__ ushort4 cvt4(float4 v) {
  ushort4 p; p.x = f2bf(v.x); p.y = f2bf(v.y); p.z = f2bf(v.z); p.w = f2bf(v.w);
  return p;
}

// ---------------- prep: weight fold/convert + nodes->bf16 + receiver histogram ----
__global__ __launch_bounds__(256) void prep_kernel(
    const float* __restrict__ W1, const float* __restrict__ Wm,
    const float* __restrict__ W2, const float* __restrict__ Wn,
    const float* __restrict__ nodes, const int* __restrict__ eidx,
    unsigned short* __restrict__ Wcat, unsigned short* __restrict__ W2b,
    unsigned short* __restrict__ Wnb, unsigned short* __restrict__ nodes_bf,
    int* __restrict__ counts, int Nn, int E, int nconv) {
  const int b = blockIdx.x, tid = threadIdx.x;
  if (b < 128) {
    for (int t = tid; t < 288; t += 256) {
      float v;
      if (t < 128) {
        v = W1[(size_t)b * 256 + t];
      } else {
        int u = t - 128;
        float s = 0.f;
#pragma unroll 8
        for (int k = 0; k < 128; ++k)
          s += W1[(size_t)b * 256 + 128 + k] * Wm[(size_t)k * 160 + u];
        v = s;
      }
      Wcat[(size_t)b * 288 + t] = f2bf(v);
    }
  } else if (b < 144) {
    int idx = (b - 128) * 1024 + tid * 4;
    *(ushort4*)&W2b[idx] = cvt4(*(const float4*)&W2[idx]);
  } else if (b < 160) {
    int idx = (b - 144) * 1024 + tid * 4;
    *(ushort4*)&Wnb[idx] = cvt4(*(const float4*)&Wn[idx]);
  } else if (b < 160 + nconv) {
    int idx = ((b - 160) * 256 + tid) * 4;
    if (idx < Nn * 128)
      *(ushort4*)&nodes_bf[idx] = cvt4(*(const float4*)&nodes[idx]);
  } else {
    int i = (b - 160 - nconv) * 256 + tid;
    if (i < E) atomicAdd(&counts[eidx[E + i]], 1);
  }
}

// ---------------- parallel exclusive scan over counts ----------------
__global__ __launch_bounds__(256) void scan1_kernel(const int* __restrict__ counts,
                                                    int* __restrict__ bsum, int Nn) {
  __shared__ int red[256];
  const int tid = threadIdx.x;
  int base = blockIdx.x * 2048 + tid * 8;
  int s = 0;
#pragma unroll
  for (int i = 0; i < 8; ++i) {
    int idx = base + i;
    if (idx < Nn) s += counts[idx];
  }
  red[tid] = s;
  __syncthreads();
#pragma unroll
  for (int off = 128; off; off >>= 1) {
    if (tid < off) red[tid] += red[tid + off];
    __syncthreads();
  }
  if (tid == 0) bsum[blockIdx.x] = red[0];
}

__global__ __launch_bounds__(256) void scan2_kernel(const int* __restrict__ bsum,
                                                    int* __restrict__ boff, int NB) {
  __shared__ int arr[256];
  const int tid = threadIdx.x;
  int v = (tid < NB) ? bsum[tid] : 0;
  arr[tid] = v;
  __syncthreads();
  for (int off = 1; off < 256; off <<= 1) {
    int t2 = (tid >= off) ? arr[tid - off] : 0;
    __syncthreads();
    arr[tid] += t2;
    __syncthreads();
  }
  if (tid < NB) boff[tid] = arr[tid] - v;   // exclusive
}

__global__ __launch_bounds__(256) void scan3_kernel(const int* __restrict__ counts,
                                                    const int* __restrict__ boff,
                                                    int* __restrict__ row_ptr,
                                                    int* __restrict__ cursor, int Nn) {
  __shared__ int arr[256];
  const int tid = threadIdx.x;
  int base = blockIdx.x * 2048 + tid * 8;
  int c[8];
  int s = 0;
#pragma unroll
  for (int i = 0; i < 8; ++i) {
    int idx = base + i;
    c[i] = (idx < Nn) ? counts[idx] : 0;
    s += c[i];
  }
  arr[tid] = s;
  __syncthreads();
  for (int off = 1; off < 256; off <<= 1) {
    int t2 = (tid >= off) ? arr[tid - off] : 0;
    __syncthreads();
    arr[tid] += t2;
    __syncthreads();
  }
  int run = arr[tid] - s + boff[blockIdx.x];
#pragma unroll
  for (int i = 0; i < 8; ++i) {
    int idx = base + i;
    if (idx < Nn) {
      row_ptr[idx] = run;
      cursor[idx] = run;
    }
    run += c[i];
  }
}

__global__ __launch_bounds__(256) void build_kernel(const int* __restrict__ eidx,
                                                    int* __restrict__ cursor,
                                                    int* __restrict__ perm,
                                                    int* __restrict__ snds, int E) {
  int i = blockIdx.x * 256 + threadIdx.x;
  if (i < E) {
    int r = eidx[E + i];
    int pos = atomicAdd(&cursor[r], 1);
    perm[pos] = i;
    snds[pos] = eidx[i];
  }
}

// ------- per-receiver input sums: shfl-prefetched indices, 4-edge unroll --------
__global__ __launch_bounds__(256) void aggsum_kernel(
    const unsigned short* __restrict__ nodes_bf, const float* __restrict__ eattr,
    const int* __restrict__ row_ptr, const int* __restrict__ rend,
    const int* __restrict__ perm, const int* __restrict__ snds,
    unsigned short* __restrict__ S, int Nn) {
  const int wid = blockIdx.x * 4 + (threadIdx.x >> 6);
  if (wid >= Nn) return;
  const int lane = threadIdx.x & 63;
  const int start = row_ptr[wid];
  const int end = rend[wid];
  const int deg = end - start;
  const int dmax = deg < 64 ? deg : 64;

  // one coalesced load grabs up to 64 CSR entries for this receiver
  int sv = 0, pv = 0;
  if (lane < deg) {
    sv = snds[start + lane];
    pv = perm[start + lane];
  }

  const unsigned* nodes32 = (const unsigned*)nodes_bf;
  const int rsub = lane >> 5;   // half-wave: which of 2 eattr rows per load
  const int col = lane & 31;
  float s0 = 0.f, s1 = 0.f, seA = 0.f, seB = 0.f;

  int t = 0;
  for (; t + 4 <= dmax; t += 4) {
    int i0 = __shfl(sv, t + 0);
    int i1 = __shfl(sv, t + 1);
    int i2 = __shfl(sv, t + 2);
    int i3 = __shfl(sv, t + 3);
    int pA = __shfl(pv, t + rsub);
    int pB = __shfl(pv, t + 2 + rsub);
    unsigned a0 = nodes32[(size_t)i0 * 64 + lane];
    unsigned a1 = nodes32[(size_t)i1 * 64 + lane];
    unsigned a2 = nodes32[(size_t)i2 * 64 + lane];
    unsigned a3 = nodes32[(size_t)i3 * 64 + lane];
    float vA = eattr[(size_t)pA * 32 + col];
    float vB = eattr[(size_t)pB * 32 + col];
    s0 += bf2f(a0 & 0xffffu) + bf2f(a1 & 0xffffu) +
          bf2f(a2 & 0xffffu) + bf2f(a3 & 0xffffu);
    s1 += bf2f(a0 >> 16) + bf2f(a1 >> 16) + bf2f(a2 >> 16) + bf2f(a3 >> 16);
    seA += vA;
    seB += vB;
  }
  for (; t < dmax; ++t) {
    int i0 = __shfl(sv, t);
    int p = __shfl(pv, t);
    unsigned a0 = nodes32[(size_t)i0 * 64 + lane];
    s0 += bf2f(a0 & 0xffffu);
    s1 += bf2f(a0 >> 16);
    if (rsub == 0) seA += eattr[(size_t)p * 32 + col];
  }
  // overflow path (deg > 64) — rare, wave-uniform
  for (int j = start + 64; j < end; ++j) {
    int sI = snds[j];
    int p = perm[j];
    unsigned a = nodes32[(size_t)sI * 64 + lane];
    s0 += bf2f(a & 0xffffu);
    s1 += bf2f(a >> 16);
    if (rsub == 0) seA += eattr[(size_t)p * 32 + col];
  }

  // eattr: combine interleaved rows, then halves
  float se = seA + seB;
  se += __shfl_xor(se, 32);

  unsigned pack = (unsigned)f2bf(s0) | ((unsigned)f2bf(s1) << 16);
  ((unsigned*)S)[(size_t)wid * 80 + lane] = pack;

  float lo = __shfl(se, 2 * (lane & 15));
  float hi = __shfl(se, 2 * (lane & 15) + 1);
  if (lane < 16) {
    unsigned p2 = (unsigned)f2bf(lo) | ((unsigned)f2bf(hi) << 16);
    ((unsigned*)S)[(size_t)wid * 80 + 64 + lane] = p2;
  }
}

// ---------------- shared GEMM pieces ----------------
__device__ __forceinline__ void gemm_chunk(const GemmSmem& sm, int tid,
                                           f32x4 acc[2][4]) {
  const int lane = tid & 63;
  const int quad = lane >> 4;
  const int lm = lane & 15;
  const int wid = tid >> 6;
  const int wy = wid >> 1, wx = wid & 1;

  bf16x8 af[2], bf[4];
#pragma unroll
  for (int mt = 0; mt < 2; ++mt)
    af[mt] = *(const bf16x8*)&sm.As[32 * wy + 16 * mt + lm][quad * 8];
#pragma unroll
  for (int nt = 0; nt < 4; ++nt)
    bf[nt] = *(const bf16x8*)&sm.Bs[64 * wx + 16 * nt + lm][quad * 8];
#pragma unroll
  for (int mt = 0; mt < 2; ++mt)
#pragma unroll
    for (int nt = 0; nt < 4; ++nt)
      acc[mt][nt] = __builtin_amdgcn_mfma_f32_16x16x32_bf16(
          af[mt], bf[nt], acc[mt][nt], 0, 0, 0);
}

// K=128 GEMM with A sourced from global bf16 rows
__device__ __forceinline__ void gemm_k128(const unsigned short* __restrict__ A,
                                          const unsigned short* __restrict__ W,
                                          int row0, int Nn, GemmSmem& g, int tid,
                                          f32x4 acc[2][4]) {
  for (int kc = 0; kc < 128; kc += BK) {
    {
      int r = tid >> 2, u = tid & 3;
      int row = row0 + r;
      if (row >= Nn) row = Nn - 1;
      BF8 t;
      t.v = *(const bf16x8*)&A[(size_t)row * 128 + kc + 8 * u];
      *(ushort4*)&g.As[r][8 * u] = t.q[0];
      *(ushort4*)&g.As[r][8 * u + 4] = t.q[1];
    }
#pragma unroll
    for (int c = 0; c < 2; ++c) {
      int f = tid + 256 * c;
      int n = f >> 2, u = f & 3;
      BF8 t;
      t.v = *(const bf16x8*)&W[(size_t)n * 128 + kc + 8 * u];
      *(ushort4*)&g.Bs[n][8 * u] = t.q[0];
      *(ushort4*)&g.Bs[n][8 * u + 4] = t.q[1];
    }
    __syncthreads();
    gemm_chunk(g, tid, acc);
    __syncthreads();
  }
}

// K=128 GEMM with A sourced from the f32 Cs tile in LDS (RNE convert at staging,
// identical rounding to the old h_bf global round-trip)
__device__ __forceinline__ void gemm_k128_lds(const EpiSmem& e,
                                              const unsigned short* __restrict__ W,
                                              GemmSmem& g, int tid,
                                              f32x4 acc[2][4]) {
  for (int kc = 0; kc < 128; kc += BK) {
    {
      int r = tid >> 2, u = tid & 3;
      float4 lo = *(const float4*)&e.Cs[r][kc + 8 * u];
      float4 hi = *(const float4*)&e.Cs[r][kc + 8 * u + 4];
      *(ushort4*)&g.As[r][8 * u] = cvt4(lo);
      *(ushort4*)&g.As[r][8 * u + 4] = cvt4(hi);
    }
#pragma unroll
    for (int c = 0; c < 2; ++c) {
      int f = tid + 256 * c;
      int n = f >> 2, u = f & 3;
      BF8 t;
      t.v = *(const bf16x8*)&W[(size_t)n * 128 + kc + 8 * u];
      *(ushort4*)&g.Bs[n][8 * u] = t.q[0];
      *(ushort4*)&g.Bs[n][8 * u + 4] = t.q[1];
    }
    __syncthreads();
    gemm_chunk(g, tid, acc);
    __syncthreads();
  }
}

__device__ __forceinline__ void ln_stats(EpiSmem& e, int tid) {
  {
    int q = tid & 3, r = tid >> 2;
    float s = 0.f, s2 = 0.f;
#pragma unroll 8
    for (int j = q * 32; j < q * 32 + 32; ++j) {
      float x = e.Cs[r][j];
      s += x;
      s2 += x * x;
    }
    e.psum[r][q] = s;
    e.psq[r][q] = s2;
  }
  __syncthreads();
  if (tid < BM) {
    float S_ = 0.f, S2 = 0.f;
#pragma unroll
    for (int q = 0; q < 4; ++q) {
      S_ += e.psum[tid][q];
      S2 += e.psq[tid][q];
    }
    float m = S_ * (1.f / 128.f);
    float var = S2 * (1.f / 128.f) - m * m;
    e.mu[tid] = m;
    e.rs[tid] = rsqrtf(var + 1e-5f);
  }
  __syncthreads();
}

// ---- fused node pipeline: per 64-row tile ----
//   phase A: h = LN1(relu([nodes|S] @ Wcat^T + b1))  (K=288) -> Cs (f32)
//   phase B: t = LN2(relu(h @ W2^T + b2))            (A from Cs in LDS) -> Cs
//   phase C: out = LNf(nodes @ Wn^T + t)             (K=128)
__global__ __launch_bounds__(THREADS, 3) void node_fused_kernel(
    const unsigned short* __restrict__ A0, const unsigned short* __restrict__ A1,
    const unsigned short* __restrict__ Wcat, const float* __restrict__ b1,
    const float* __restrict__ g1, const float* __restrict__ bl1,
    const unsigned short* __restrict__ W2b, const unsigned short* __restrict__ Wnb,
    const float* __restrict__ b2, const float* __restrict__ g2,
    const float* __restrict__ bl2, const float* __restrict__ gf,
    const float* __restrict__ blf, float* __restrict__ out, int Nn) {
  __shared__ GemmSmem g;
  __shared__ EpiSmem e;
  const int tid = threadIdx.x;
  const int row0 = blockIdx.x * BM;
  const int lane = tid & 63;
  const int quad = lane >> 4;
  const int lm = lane & 15;
  const int wid = tid >> 6;
  const int wy = wid >> 1, wx = wid & 1;

  f32x4 acc[2][4];
#pragma unroll
  for (int mt = 0; mt < 2; ++mt)
#pragma unroll
    for (int nt = 0; nt < 4; ++nt) acc[mt][nt] = (f32x4)0.f;

  // ---- phase A: [nodes|S] @ Wcat^T (K=288) ----
  for (int kc = 0; kc < 288; kc += BK) {
    {
      int r = tid >> 2, u = tid & 3;
      int k = kc + 8 * u;
      int row = row0 + r;
      if (row >= Nn) row = Nn - 1;
      BF8 t;
      if (kc >= 128)
        t.v = *(const bf16x8*)&A1[(size_t)row * 160 + (k - 128)];
      else
        t.v = *(const bf16x8*)&A0[(size_t)row * 128 + k];
      *(ushort4*)&g.As[r][8 * u] = t.q[0];
      *(ushort4*)&g.As[r][8 * u + 4] = t.q[1];
    }
#pragma unroll
    for (int c = 0; c < 2; ++c) {
      int f = tid + 256 * c;
      int n = f >> 2, u = f & 3;
      BF8 t;
      t.v = *(const bf16x8*)&Wcat[(size_t)n * 288 + kc + 8 * u];
      *(ushort4*)&g.Bs[n][8 * u] = t.q[0];
      *(ushort4*)&g.Bs[n][8 * u + 4] = t.q[1];
    }
    __syncthreads();
    gemm_chunk(g, tid, acc);
    __syncthreads();
  }

  // epilogue A: relu + b1 -> Cs, LN1, normalize in place (h, f32)
  {
    float bval[4];
#pragma unroll
    for (int nt = 0; nt < 4; ++nt) bval[nt] = b1[64 * wx + 16 * nt + lm];
#pragma unroll
    for (int mt = 0; mt < 2; ++mt)
#pragma unroll
      for (int i = 0; i < 4; ++i) {
        int r = 32 * wy + 16 * mt + quad * 4 + i;
#pragma unroll
        for (int nt = 0; nt < 4; ++nt) {
          int col = 64 * wx + 16 * nt + lm;
          e.Cs[r][col] = fmaxf(acc[mt][nt][i] + bval[nt], 0.f);
        }
      }
  }
  __syncthreads();
  ln_stats(e, tid);
#pragma unroll 4
  for (int s = 0; s < 32; ++s) {
    int flat = tid + THREADS * s;
    int r = flat >> 7, j = flat & 127;
    float x = e.Cs[r][j];
    e.Cs[r][j] = (x - e.mu[r]) * e.rs[r] * g1[j] + bl1[j];
  }
  __syncthreads();

  // ---- phase B: h @ W2^T (A from LDS), relu+b2, LN2 -> Cs (node_out tile) ----
#pragma unroll
  for (int mt = 0; mt < 2; ++mt)
#pragma unroll
    for (int nt = 0; nt < 4; ++nt) acc[mt][nt] = (f32x4)0.f;

  gemm_k128_lds(e, W2b, g, tid, acc);

  {
    float bval[4];
#pragma unroll
    for (int nt = 0; nt < 4; ++nt) bval[nt] = b2[64 * wx + 16 * nt + lm];
#pragma unroll
    for (int mt = 0; mt < 2; ++mt)
#pragma unroll
      for (int i = 0; i < 4; ++i) {
        int r = 32 * wy + 16 * mt + quad * 4 + i;
#pragma unroll
        for (int nt = 0; nt < 4; ++nt) {
          int col = 64 * wx + 16 * nt + lm;
          e.Cs[r][col] = fmaxf(acc[mt][nt][i] + bval[nt], 0.f);
        }
      }
  }
  __syncthreads();
  ln_stats(e, tid);
#pragma unroll 4
  for (int s = 0; s < 32; ++s) {
    int flat = tid + THREADS * s;
    int r = flat >> 7, j = flat & 127;
    float x = e.Cs[r][j];
    e.Cs[r][j] = (x - e.mu[r]) * e.rs[r] * g2[j] + bl2[j];
  }
  __syncthreads();

  // ---- phase C: nodes @ Wn^T + node_out, final LN ----
#pragma unroll
  for (int mt = 0; mt < 2; ++mt)
#pragma unroll
    for (int nt = 0; nt < 4; ++nt) acc[mt][nt] = (f32x4)0.f;

  gemm_k128(A0, Wnb, row0, Nn, g, tid, acc);

#pragma unroll
  for (int mt = 0; mt < 2; ++mt)
#pragma unroll
    for (int i = 0; i < 4; ++i) {
      int r = 32 * wy + 16 * mt + quad * 4 + i;
#pragma unroll
      for (int nt = 0; nt < 4; ++nt) {
        int col = 64 * wx + 16 * nt + lm;
        e.Cs[r][col] = acc[mt][nt][i] + e.Cs[r][col];
      }
    }
  __syncthreads();
  ln_stats(e, tid);

#pragma unroll 4
  for (int s = 0; s < 32; ++s) {
    int flat = tid + THREADS * s;
    int r = flat >> 7, j = flat & 127;
    int row = row0 + r;
    if (row < Nn) {
      float x = e.Cs[r][j];
      out[(size_t)row * 128 + j] =
          (x - e.mu[r]) * e.rs[r] * gf[j] + blf[j];
    }
  }
}

extern "C" void kernel_launch(void* const* d_in, const int* in_sizes, int n_in,
                              void* d_out, int out_size, void* d_ws, size_t ws_size,
                              hipStream_t stream) {
  const float* nodes = (const float*)d_in[0];
  const int* eidx    = (const int*)d_in[1];
  const float* eattr = (const float*)d_in[2];
  const float* Wm    = (const float*)d_in[3];
  const float* Wn    = (const float*)d_in[4];
  const float* W1    = (const float*)d_in[5];
  const float* b1    = (const float*)d_in[6];
  const float* g1    = (const float*)d_in[7];
  const float* bl1   = (const float*)d_in[8];
  const float* W2    = (const float*)d_in[9];
  const float* b2    = (const float*)d_in[10];
  const float* g2    = (const float*)d_in[11];
  const float* bl2   = (const float*)d_in[12];
  const float* gf    = (const float*)d_in[13];
  const float* blf   = (const float*)d_in[14];
  float* out = (float*)d_out;

  const int Nn = in_sizes[0] / 128;   // 100000
  const int E  = in_sizes[2] / 32;    // 800000

  // workspace layout (all 16B-aligned)
  int* counts  = (int*)d_ws;                       // [Nn]
  int* row_ptr = counts + Nn;                      // [Nn]
  int* cursor  = row_ptr + Nn;                     // [Nn] (segment ends after build)
  int* bsum    = cursor + Nn;                      // [256]
  int* boff    = bsum + 256;                       // [256]
  int* perm    = boff + 256;                       // [E]
  int* snds    = perm + E;                         // [E]
  unsigned short* Wcat     = (unsigned short*)(snds + E);       // [128*288]
  unsigned short* W2b      = Wcat + 128 * 288;                  // [128*128]
  unsigned short* Wnb      = W2b + 128 * 128;                   // [128*128]
  unsigned short* nodes_bf = Wnb + 128 * 128;                   // [Nn*128]
  unsigned short* S_bf     = nodes_bf + (size_t)Nn * 128;       // [Nn*160]

  hipMemsetAsync(counts, 0, (size_t)Nn * sizeof(int), stream);

  const int nconv = (Nn * 32 + 255) / 256;   // nodes float4 chunks
  const int nhist = (E + 255) / 256;
  const int NB = (Nn + 2047) / 2048;
  const int ngrid = (Nn + BM - 1) / BM;

  prep_kernel<<<160 + nconv + nhist, 256, 0, stream>>>(
      W1, Wm, W2, Wn, nodes, eidx, Wcat, W2b, Wnb, nodes_bf, counts, Nn, E, nconv);
  scan1_kernel<<<NB, 256, 0, stream>>>(counts, bsum, Nn);
  scan2_kernel<<<1, 256, 0, stream>>>(bsum, boff, NB);
  scan3_kernel<<<NB, 256, 0, stream>>>(counts, boff, row_ptr, cursor, Nn);
  build_kernel<<<nhist, 256, 0, stream>>>(eidx, cursor, perm, snds, E);
  aggsum_kernel<<<(Nn + 3) / 4, 256, 0, stream>>>(nodes_bf, eattr, row_ptr, cursor,
                                                  perm, snds, S_bf, Nn);
  node_fused_kernel<<<ngrid, THREADS, 0, stream>>>(
      nodes_bf, S_bf, Wcat, b1, g1, bl1, W2b, Wnb, b2, g2, bl2, gf, blf, out, Nn);
}